// Round 1
// 225.232 us; speedup vs baseline: 1.0102x; 1.0102x over previous
//
#include <hip/hip_runtime.h>

// GridSpatialIntegral: out[:,0] = cumsum_x(in[:,0]); out[:,1] = cumsum_y(in[:,1])
// [B=64, C=2, 512, 512] fp32. Memory-bound: 134 MB read + 134 MB write, floor ~43-48 us.
//
// Single fused launch, 512-thread blocks (8 waves):
//   blocks [0, 512):     channel 1 (y-scan) — 64-col x 512-row tile per block
//   blocks [512, 4608):  channel 0 (x-scan) — 8 rows per block, 1 wave per row
//
// R1 change: x-path accesses made fully 64B-line dense. Previously lane i did
// ip[2i], ip[2i+1] (32B-stride interleave -> each instr touches 16B of every
// 32B = half of every 64B line; NT stores then emit partial-sector writes that
// L2 won't merge). Now lane i does ip[i] (segment 0, contiguous 1KB/wave-instr)
// and ip[64+i] (segment 1), with a two-segment wave scan (12 shfls, hidden).

#define W 512
#define NB 64
#define YBLOCKS (NB * 8)          // 512
#define XBLOCKS (NB * W / 8)      // 4096

typedef float v4f __attribute__((ext_vector_type(4)));   // clang vector: NT-builtin OK

__global__ __launch_bounds__(512)
void gsi_kernel(const float* __restrict__ in, float* __restrict__ out) {
    __shared__ v4f seg[32][16];    // y-path segment sums (8 KB)
    const int tid = threadIdx.x;

    if (blockIdx.x < YBLOCKS) {
        // -------- channel 1: inclusive scan along strided y --------
        // 512 threads = 16 tx (float4 cols) x 32 ty (16-row segments).
        // Per load instr a wave covers 4 rows x 256B contiguous: full 64B lines.
        const int bi = blockIdx.x;
        const int b  = bi >> 3;
        const int x0 = (bi & 7) << 6;        // 64-column tile
        const int tx = tid & 15;
        const int ty = tid >> 4;

        const size_t base = (size_t)b * (2 * W * W) + (size_t)(W * W)
                          + (size_t)(ty * 16) * W + (size_t)x0 + (size_t)(tx * 4);
        const v4f* ip = (const v4f*)(in + base);
        v4f*       op = (v4f*)(out + base);
        // row stride in v4f units: W/4 = 128

        v4f d[16];
        v4f sum = (v4f)(0.f);
        #pragma unroll
        for (int k = 0; k < 16; ++k) {
            d[k] = __builtin_nontemporal_load(&ip[k * 128]);
            sum += d[k];
        }

        seg[ty][tx] = sum;
        __syncthreads();

        v4f acc = (v4f)(0.f);
        for (int j = 0; j < ty; ++j) acc += seg[j][tx];

        #pragma unroll
        for (int k = 0; k < 16; ++k) {
            acc += d[k];
            __builtin_nontemporal_store(acc, &op[k * 128]);
        }
    } else {
        // -------- channel 0: inclusive scan along contiguous x --------
        // One wave per 512-float row. Two dense 1KB segments per row:
        //   seg0 = floats [0,256)   -> lane's chunk at ip[lane]
        //   seg1 = floats [256,512) -> lane's chunk at ip[64+lane]
        const int wave = tid >> 6;                       // 0..7
        const int lane = tid & 63;
        const int row  = ((blockIdx.x - YBLOCKS) << 3) + wave;   // 0..32767
        const int b    = row >> 9;
        const int y    = row & 511;
        const size_t base = (size_t)b * (2 * W * W) + (size_t)y * W;

        const v4f* ip = (const v4f*)(in + base);
        v4f*       op = (v4f*)(out + base);

        v4f v0 = __builtin_nontemporal_load(&ip[lane]);        // dense 1KB
        v4f v1 = __builtin_nontemporal_load(&ip[64 + lane]);   // dense 1KB

        // per-lane inclusive prefixes within each 4-elem chunk
        float e0 = v0.x;
        float e1 = e0 + v0.y;
        float e2 = e1 + v0.z;
        float e3 = e2 + v0.w;
        float f0 = v1.x;
        float f1 = f0 + v1.y;
        float f2 = f1 + v1.z;
        float f3 = f2 + v1.w;

        // two independent wave scans of the chunk totals (ILP-paired shfls)
        const float t0 = e3, t1 = f3;
        float s0 = t0, s1 = t1;
        #pragma unroll
        for (int off = 1; off < 64; off <<= 1) {
            float u0 = __shfl_up(s0, off, 64);
            float u1 = __shfl_up(s1, off, 64);
            if (lane >= off) { s0 += u0; s1 += u1; }
        }
        const float p0 = s0 - t0;                 // excl. prefix within seg 0
        const float T0 = __shfl(s0, 63, 64);      // seg-0 total (broadcast)
        const float p1 = T0 + (s1 - t1);          // seg-1 offset

        v4f o0 = {e0 + p0, e1 + p0, e2 + p0, e3 + p0};
        v4f o1 = {f0 + p1, f1 + p1, f2 + p1, f3 + p1};
        __builtin_nontemporal_store(o0, &op[lane]);        // dense 1KB
        __builtin_nontemporal_store(o1, &op[64 + lane]);   // dense 1KB
    }
}

extern "C" void kernel_launch(void* const* d_in, const int* in_sizes, int n_in,
                              void* d_out, int out_size, void* d_ws, size_t ws_size,
                              hipStream_t stream) {
    const float* in  = (const float*)d_in[0];
    float*       out = (float*)d_out;
    (void)in_sizes; (void)n_in; (void)out_size; (void)d_ws; (void)ws_size;
    gsi_kernel<<<dim3(YBLOCKS + XBLOCKS), dim3(512), 0, stream>>>(in, out);
}

// Round 2
// 221.729 us; speedup vs baseline: 1.0262x; 1.0158x over previous
//
#include <hip/hip_runtime.h>

// GridSpatialIntegral: out[:,0] = cumsum_x(in[:,0]); out[:,1] = cumsum_y(in[:,1])
// [B=64, C=2, 512, 512] fp32. Memory-bound: 134 MB read + 134 MB write, floor ~43-48 us.
//
// Single fused launch, 512-thread blocks (8 waves):
//   blocks [0, 256):     channel 1 (y-scan) — 128-col x 512-row column tile per block
//   blocks [256, 4352):  channel 0 (x-scan) — 8 rows per block, 1 wave per row
//
// R2 change: y-path DRAM density. Was 64-col tiles -> every wave-load touched
// 4 x 256B chunks (256B runs at 2KB stride; HBM page merging left to cross-XCD
// timing luck). Now 128-col tiles -> 2 x 512B contiguous per wave instruction,
// same d[16] register footprint via two sequential 256-row halves with a
// register carry (carry = column total of half 0). VGPR/occupancy unchanged:
// 2 blocks/CU, so x- and y-blocks still co-reside and mix their streams.
// x-path unchanged from R1 (every wave instr 1KB dense).

#define W 512
#define NB 64
#define YBLOCKS (NB * 4)          // 256
#define XBLOCKS (NB * W / 8)      // 4096

typedef float v4f __attribute__((ext_vector_type(4)));   // clang vector: NT-builtin OK

__global__ __launch_bounds__(512)
void gsi_kernel(const float* __restrict__ in, float* __restrict__ out) {
    __shared__ v4f seg[16][32];    // y-path segment sums (8 KB)
    const int tid = threadIdx.x;

    if (blockIdx.x < YBLOCKS) {
        // -------- channel 1: inclusive scan along strided y --------
        // 512 threads = 32 tx (float4 cols, 512B/row-chunk) x 16 ty (16-row segs).
        // Column processed as two 256-row halves; carry propagates in registers.
        const int bi = blockIdx.x;
        const int b  = bi >> 2;
        const int x0 = (bi & 3) << 7;        // 128-column tile
        const int tx = tid & 31;
        const int ty = tid >> 5;             // 0..15

        const size_t base = (size_t)b * (2 * W * W) + (size_t)(W * W)
                          + (size_t)(ty * 16) * W + (size_t)x0 + (size_t)(tx * 4);
        const v4f* ip = (const v4f*)(in + base);
        v4f*       op = (v4f*)(out + base);
        // row stride in v4f units: W/4 = 128; half stride: 256 rows = 32768 v4f

        v4f d[16];
        v4f carry = (v4f)(0.f);

        #pragma unroll
        for (int h = 0; h < 2; ++h) {
            const int hb = h * 32768;
            v4f sum = (v4f)(0.f);
            #pragma unroll
            for (int k = 0; k < 16; ++k) {
                d[k] = __builtin_nontemporal_load(&ip[hb + k * 128]);
                sum += d[k];
            }

            seg[ty][tx] = sum;
            __syncthreads();

            v4f acc = carry;
            v4f tot = (v4f)(0.f);
            #pragma unroll
            for (int j = 0; j < 16; ++j) {
                v4f s = seg[j][tx];
                tot += s;
                if (j < ty) acc += s;
            }
            carry += tot;
            __syncthreads();     // seg reusable in next half

            #pragma unroll
            for (int k = 0; k < 16; ++k) {
                acc += d[k];
                __builtin_nontemporal_store(acc, &op[hb + k * 128]);
            }
        }
    } else {
        // -------- channel 0: inclusive scan along contiguous x --------
        // One wave per 512-float row. Two dense 1KB segments per row:
        //   seg0 = floats [0,256)   -> lane's chunk at ip[lane]
        //   seg1 = floats [256,512) -> lane's chunk at ip[64+lane]
        const int wave = tid >> 6;                       // 0..7
        const int lane = tid & 63;
        const int row  = ((blockIdx.x - YBLOCKS) << 3) + wave;   // 0..32767
        const int b    = row >> 9;
        const int y    = row & 511;
        const size_t base = (size_t)b * (2 * W * W) + (size_t)y * W;

        const v4f* ip = (const v4f*)(in + base);
        v4f*       op = (v4f*)(out + base);

        v4f v0 = __builtin_nontemporal_load(&ip[lane]);        // dense 1KB
        v4f v1 = __builtin_nontemporal_load(&ip[64 + lane]);   // dense 1KB

        // per-lane inclusive prefixes within each 4-elem chunk
        float e0 = v0.x;
        float e1 = e0 + v0.y;
        float e2 = e1 + v0.z;
        float e3 = e2 + v0.w;
        float f0 = v1.x;
        float f1 = f0 + v1.y;
        float f2 = f1 + v1.z;
        float f3 = f2 + v1.w;

        // two independent wave scans of the chunk totals (ILP-paired shfls)
        const float t0 = e3, t1 = f3;
        float s0 = t0, s1 = t1;
        #pragma unroll
        for (int off = 1; off < 64; off <<= 1) {
            float u0 = __shfl_up(s0, off, 64);
            float u1 = __shfl_up(s1, off, 64);
            if (lane >= off) { s0 += u0; s1 += u1; }
        }
        const float p0 = s0 - t0;                 // excl. prefix within seg 0
        const float T0 = __shfl(s0, 63, 64);      // seg-0 total (broadcast)
        const float p1 = T0 + (s1 - t1);          // seg-1 offset

        v4f o0 = {e0 + p0, e1 + p0, e2 + p0, e3 + p0};
        v4f o1 = {f0 + p1, f1 + p1, f2 + p1, f3 + p1};
        __builtin_nontemporal_store(o0, &op[lane]);        // dense 1KB
        __builtin_nontemporal_store(o1, &op[64 + lane]);   // dense 1KB
    }
}

extern "C" void kernel_launch(void* const* d_in, const int* in_sizes, int n_in,
                              void* d_out, int out_size, void* d_ws, size_t ws_size,
                              hipStream_t stream) {
    const float* in  = (const float*)d_in[0];
    float*       out = (float*)d_out;
    (void)in_sizes; (void)n_in; (void)out_size; (void)d_ws; (void)ws_size;
    gsi_kernel<<<dim3(YBLOCKS + XBLOCKS), dim3(512), 0, stream>>>(in, out);
}